// Round 1
// baseline (1392.354 us; speedup 1.0000x reference)
//
#include <hip/hip_runtime.h>
#include <hip/hip_bf16.h>

#define N_ATOMS 25000
#define N_PAIRS 500000
#define DEPTH 4

typedef _Float16 f16x8 __attribute__((ext_vector_type(8)));
typedef float f32x16 __attribute__((ext_vector_type(16)));
typedef unsigned short u16;

__device__ __forceinline__ float tanh_fast(float x) {
    // tanh(x) = 1 - 2/(exp(2x)+1); saturates correctly at +/-inf
    float e = __expf(2.0f * x);
    return 1.0f - 2.0f * __builtin_amdgcn_rcpf(e + 1.0f);
}

__device__ __forceinline__ void split_h(float x, u16& hi, u16& lo) {
    _Float16 h = (_Float16)x;                 // RNE
    _Float16 l = (_Float16)(x - (float)h);    // residual, RNE
    hi = *(u16*)&h;
    lo = *(u16*)&l;
}

// LDS bank-swizzle on 16B-unit index: XOR the (ks/lh | chks/chlh) bits (u>>5)
// into the bank bits (u&7). Involution, bijective within each 128B block,
// keeps per-lane b128 units intact. Apply identically on write and read.
__device__ __forceinline__ int swz8(int u) { return u ^ ((u >> 5) & 7); }

// ---------------- prep: split weights to hi/lo fp16, fragment-major images
// img1 per depth: [hl][ntw][ks(8)][l(64)][j(8)]        = 16384 u16
// img2 per depth: [hl][ntw][t(4)][ks(4)][l][j]         = 32768 u16  (cols permuted: n=4*ch+t)
// imgab per depth: [stage][hl][ntw][ks(4)][l][j]       = 16384 u16
__global__ __launch_bounds__(256)
void prep_kernel(const float* __restrict__ piW1, const float* __restrict__ piW2,
                 const float* __restrict__ iiW1, const float* __restrict__ iiW2,
                 u16* __restrict__ img1, u16* __restrict__ img2, u16* __restrict__ imgab) {
    int gid = blockIdx.x * 256 + threadIdx.x;     // 512 blocks * 256 = 131072 = 4*32768
    int d = gid >> 15, e = gid & 32767;
    u16 hi, lo;
    if (e < 8192) {                 // W1 [k=128][n=64]
        int k = e >> 6, n = e & 63;
        split_h(piW1[d * 8192 + e], hi, lo);
        int ntw = n >> 5, colb = n & 31;
        int ks = k >> 4, lh = (k >> 3) & 1, j = k & 7;
        int off = ((ntw * 8 + ks) * 64 + lh * 32 + colb) * 8 + j;
        img1[d * 16384 + 0 * 8192 + off] = hi;
        img1[d * 16384 + 1 * 8192 + off] = lo;
    } else if (e < 24576) {         // W2 [k=64][n=256], permuted n = 4*ch + t
        int s = e - 8192;
        int k = s >> 8, n = s & 255;
        split_h(piW2[d * 16384 + s], hi, lo);
        int ch = n >> 2, t = n & 3;
        int ntw = ch >> 5, colb = ch & 31;
        int ks = k >> 4, lh = (k >> 3) & 1, j = k & 7;
        int off = (((ntw * 4 + t) * 4 + ks) * 64 + lh * 32 + colb) * 8 + j;
        img2[d * 32768 + 0 * 16384 + off] = hi;
        img2[d * 32768 + 1 * 16384 + off] = lo;
    } else {                        // Wa (stage0) / Wb (stage1), [k=64][n=64]
        int stage = (e < 28672) ? 0 : 1;
        int s = e - (stage ? 28672 : 24576);
        int k = s >> 6, n = s & 63;
        float x = stage ? iiW2[d * 4096 + s] : iiW1[d * 4096 + s];
        split_h(x, hi, lo);
        int ntw = n >> 5, colb = n & 31;
        int ks = k >> 4, lh = (k >> 3) & 1, j = k & 7;
        int off = ((ntw * 4 + ks) * 64 + lh * 32 + colb) * 8 + j;
        imgab[d * 16384 + (stage * 2 + 0) * 4096 + off] = hi;
        imgab[d * 16384 + (stage * 2 + 1) * 4096 + off] = lo;
    }
}

__global__ __launch_bounds__(256)
void prep_b2(const float* __restrict__ piB2, float* __restrict__ b2p) {
    int d = blockIdx.x, n = threadIdx.x;
    int ch = n >> 2, t = n & 3;
    int np = (ch >> 5) * 128 + t * 32 + (ch & 31);
    b2p[d * 256 + np] = piB2[d * 256 + n];
}

// ---------------- atom-level MLP (fp32 VALU), h stored split fp16 (hi=RNE, lo=RNE(h-hi))
template <int K, bool IS_D0>
__global__ __launch_bounds__(256)
void atom_mlp(const float* __restrict__ p_in,
              const float* __restrict__ W1, const float* __restrict__ b1,
              const float* __restrict__ W2, const float* __restrict__ b2,
              const float* __restrict__ res0_w,
              _Float16* __restrict__ h_hi, _Float16* __restrict__ h_lo,
              float* __restrict__ acc_out) {
    __shared__ float sP[4][64];
    __shared__ float sH[4][64];
    int tid = threadIdx.x;
    int al = tid >> 6, c = tid & 63;
    int a = blockIdx.x * 4 + al;
    if (c < K) sP[al][c] = p_in[a * K + c];
    __syncthreads();
    float s = b1[c];
#pragma unroll
    for (int k = 0; k < K; ++k) s += sP[al][k] * W1[k * 64 + c];
    float t1 = tanh_fast(s);
    float r;
    if (IS_D0) {
        r = 0.f;
#pragma unroll
        for (int k = 0; k < 16; ++k) r += sP[al][k] * res0_w[k * 64 + c];
    } else {
        r = sP[al][c];
    }
    acc_out[a * 64 + c] = r;
    sH[al][c] = t1;
    __syncthreads();
    float s2 = b2[c];
#pragma unroll
    for (int k = 0; k < 64; ++k) s2 += sH[al][k] * W2[k * 64 + c];
    float hv = tanh_fast(s2);
    _Float16 hb = (_Float16)hv;          // RNE hi
    h_hi[a * 64 + c] = hb;
    h_lo[a * 64 + c] = (_Float16)(hv - (float)hb);
}

// ---------------- output head (fp32)
__global__ __launch_bounds__(256)
void out_kernel(const float* __restrict__ p,
                const float* __restrict__ W1, const float* __restrict__ b1,
                const float* __restrict__ W2, const float* __restrict__ b2,
                const float* __restrict__ wo,
                float* __restrict__ out, int store) {
    __shared__ float sP[4][64];
    __shared__ float sH[4][64];
    int tid = threadIdx.x;
    int al = tid >> 6, c = tid & 63;
    int a = blockIdx.x * 4 + al;
    sP[al][c] = p[a * 64 + c];
    __syncthreads();
    float s = b1[c];
#pragma unroll
    for (int k = 0; k < 64; ++k) s += sP[al][k] * W1[k * 64 + c];
    sH[al][c] = tanh_fast(s);
    __syncthreads();
    float s2 = b2[c];
#pragma unroll
    for (int k = 0; k < 64; ++k) s2 += sH[al][k] * W2[k * 64 + c];
    float v = tanh_fast(s2) * wo[c];
#pragma unroll
    for (int off = 32; off > 0; off >>= 1) v += __shfl_down(v, off, 64);
    if (c == 0) {
        if (store) out[a] = v;
        else out[a] += v;
    }
}

// ---------------- fused pair pipeline: fp16 MFMA 32x32x16, split weights + split h_i
#define MFMA __builtin_amdgcn_mfma_f32_32x32x16_f16

__global__ __launch_bounds__(512, 2)
void pair_kernel(const _Float16* __restrict__ hhi,
                 const _Float16* __restrict__ hlo,
                 const int* __restrict__ ind2,
                 const float* __restrict__ basis,
                 const u16* __restrict__ img1,   // this depth
                 const u16* __restrict__ img2,
                 const u16* __restrict__ imgab,
                 const float* __restrict__ piB1,
                 const float* __restrict__ b2p,
                 float* __restrict__ accp) {
    __shared__ __attribute__((aligned(16))) _Float16 sW2[32768];   // 64 KB
    __shared__ __attribute__((aligned(16))) _Float16 sA[16384];    // 32 KB  pij-hi frags / inter frags (swizzled)
    __shared__ __attribute__((aligned(16))) _Float16 sAlo[8192];   // 16 KB  pij-lo (i-half) frags (swizzled)
    __shared__ __attribute__((aligned(16))) _Float16 sPing[8192];  // 16 KB  (swizzled)
    __shared__ float sBas[128 * 4];                                //  2 KB
    __shared__ int sIdx[128];                                      // 0.5 KB
    // total 130.5 KB -> 1 block/CU, 2 waves/SIMD

    const int tid = threadIdx.x;
    for (int i = tid; i < 4096; i += 512) ((uint4*)sW2)[i] = ((const uint4*)img2)[i];

    const int l = tid & 63;
    const int w = tid >> 6;
    const int mt = w >> 1, ntw = w & 1;
    const int col = l & 31, kg = l >> 5;
    const int ch = ntw * 32 + col;
    const int chks = ch >> 4, chlh = (ch >> 3) & 1, chj = ch & 7;   // fragment write coords

    // persistent register weights: W1 hi+lo (16 frags), ii_w1/ii_w2 hi+lo (16 frags)
    f16x8 w1h[8], w1l[8], fa[2][4], fb[2][4];
#pragma unroll
    for (int ks = 0; ks < 8; ++ks) {
        w1h[ks] = *(const f16x8*)(img1 + ntw * 4096 + ks * 512 + l * 8);
        w1l[ks] = *(const f16x8*)(img1 + 8192 + ntw * 4096 + ks * 512 + l * 8);
    }
#pragma unroll
    for (int hl = 0; hl < 2; ++hl)
#pragma unroll
        for (int ks = 0; ks < 4; ++ks) {
            fa[hl][ks] = *(const f16x8*)(imgab + (0 * 2 + hl) * 4096 + ntw * 2048 + ks * 512 + l * 8);
            fb[hl][ks] = *(const f16x8*)(imgab + (1 * 2 + hl) * 4096 + ntw * 2048 + ks * 512 + l * 8);
        }
    const float b1v = piB1[ch];
    float b2v[4];
#pragma unroll
    for (int t = 0; t < 4; ++t) b2v[t] = b2p[ntw * 128 + t * 32 + col];

    const int nTiles = (N_PAIRS + 127) >> 7;

    auto gather = [&](int tile) {
        int base = tile << 7;
#pragma unroll
        for (int it = 0; it < 6; ++it) {
            int id = it * 512 + tid;
            if (id < 2048) {            // hi: both halves, K=128
                int m = id >> 4, half = (id >> 3) & 1, seg = id & 7;
                int p = base + m;
                uint4 v = make_uint4(0u, 0u, 0u, 0u);
                if (p < N_PAIRS) {
                    int row = ind2[2 * p + half];
                    v = *(const uint4*)(hhi + row * 64 + seg * 8);
                }
                int mtd = m >> 5, lrow = m & 31;
                int ks = half * 4 + (seg >> 1), lh = seg & 1;
                int u = (mtd * 8 + ks) * 64 + lh * 32 + lrow;
                *(uint4*)(sA + swz8(u) * 8) = v;
            } else {                    // lo: i-half only, K=64
                int e = id - 2048;
                int m = e >> 3, seg = e & 7;
                int p = base + m;
                uint4 v = make_uint4(0u, 0u, 0u, 0u);
                if (p < N_PAIRS) {
                    int row = ind2[2 * p];
                    v = *(const uint4*)(hlo + row * 64 + seg * 8);
                }
                int mtd = m >> 5, lrow = m & 31;
                int ks = seg >> 1, lh = seg & 1;
                int u = (mtd * 4 + ks) * 64 + lh * 32 + lrow;
                *(uint4*)(sAlo + swz8(u) * 8) = v;
            }
        }
    };
    gather(blockIdx.x);
    __syncthreads();

    for (int tile = blockIdx.x; tile < nTiles; tile += gridDim.x) {
        const int base = tile << 7;

        // ---- G1 phase: stage basis/idx; [128x128]@[128x64]+b1, tanh -> sPing
        if (tid < 128) {
            int p = base + tid;
            float4 bv = (p < N_PAIRS) ? ((const float4*)basis)[p] : make_float4(0.f, 0.f, 0.f, 0.f);
            *(float4*)&sBas[tid * 4] = bv;
            sIdx[tid] = (p < N_PAIRS) ? ind2[2 * p] : 0;
        }
        {
            f32x16 acc = {};
#pragma unroll
            for (int ks = 0; ks < 8; ++ks) {
                f16x8 a = *(const f16x8*)(sA + swz8(mt * 512 + ks * 64 + l) * 8);
                acc = MFMA(a, w1h[ks], acc, 0, 0, 0);
                acc = MFMA(a, w1l[ks], acc, 0, 0, 0);
            }
#pragma unroll
            for (int ks = 0; ks < 4; ++ks) {   // h_i lo correction (i-half = k 0..63)
                f16x8 a = *(const f16x8*)(sAlo + swz8(mt * 256 + ks * 64 + l) * 8);
                acc = MFMA(a, w1h[ks], acc, 0, 0, 0);
            }
#pragma unroll
            for (int r = 0; r < 16; ++r) {
                int lrow = (r & 3) + 8 * (r >> 2) + 4 * kg;
                int u = (mt * 4 + chks) * 64 + chlh * 32 + lrow;
                sPing[swz8(u) * 8 + chj] = (_Float16)tanh_fast(acc[r] + b1v);
            }
        }
        __syncthreads();

        // ---- G2 phase: [128x64]@[64x256]+b2, tanh, in-lane basis contraction -> sA (inter frags)
        {
            f32x16 acc[4] = {{}, {}, {}, {}};
#pragma unroll
            for (int ks = 0; ks < 4; ++ks) {
                f16x8 a = *(const f16x8*)(sPing + swz8(mt * 256 + ks * 64 + l) * 8);
#pragma unroll
                for (int t = 0; t < 4; ++t) {
                    acc[t] = MFMA(a, *(const f16x8*)(sW2 + ((ntw * 4 + t) * 4 + ks) * 512 + l * 8), acc[t], 0, 0, 0);
                    acc[t] = MFMA(a, *(const f16x8*)(sW2 + 16384 + ((ntw * 4 + t) * 4 + ks) * 512 + l * 8), acc[t], 0, 0, 0);
                }
            }
#pragma unroll
            for (int r = 0; r < 16; ++r) {
                int lrow = (r & 3) + 8 * (r >> 2) + 4 * kg;
                int row = mt * 32 + lrow;
                float4 bas = *(const float4*)&sBas[row * 4];
                float s = tanh_fast(acc[0][r] + b2v[0]) * bas.x
                        + tanh_fast(acc[1][r] + b2v[1]) * bas.y
                        + tanh_fast(acc[2][r] + b2v[2]) * bas.z
                        + tanh_fast(acc[3][r] + b2v[3]) * bas.w;
                int u = (mt * 4 + chks) * 64 + chlh * 32 + lrow;
                sA[swz8(u) * 8 + chj] = (_Float16)s;
            }
        }
        __syncthreads();

        // ---- G3 phase: inter @ ii_w1, tanh -> sPing
        {
            f32x16 acc = {};
#pragma unroll
            for (int ks = 0; ks < 4; ++ks) {
                f16x8 a = *(const f16x8*)(sA + swz8(mt * 256 + ks * 64 + l) * 8);
                acc = MFMA(a, fa[0][ks], acc, 0, 0, 0);
                acc = MFMA(a, fa[1][ks], acc, 0, 0, 0);
            }
#pragma unroll
            for (int r = 0; r < 16; ++r) {
                int lrow = (r & 3) + 8 * (r >> 2) + 4 * kg;
                int u = (mt * 4 + chks) * 64 + chlh * 32 + lrow;
                sPing[swz8(u) * 8 + chj] = (_Float16)tanh_fast(acc[r]);
            }
        }
        __syncthreads();

        // ---- G4 phase: @ ii_w2, tanh, atomic scatter; overlap next-tile gather
        {
            f16x8 afr[4];
#pragma unroll
            for (int ks = 0; ks < 4; ++ks)
                afr[ks] = *(const f16x8*)(sPing + swz8(mt * 256 + ks * 64 + l) * 8);
            int idxr[16];
#pragma unroll
            for (int r = 0; r < 16; ++r)
                idxr[r] = sIdx[mt * 32 + (r & 3) + 8 * (r >> 2) + 4 * kg];

            gather(tile + gridDim.x);   // writes sA/sAlo only (dead until next G1)

            f32x16 acc = {};
#pragma unroll
            for (int ks = 0; ks < 4; ++ks) {
                acc = MFMA(afr[ks], fb[0][ks], acc, 0, 0, 0);
                acc = MFMA(afr[ks], fb[1][ks], acc, 0, 0, 0);
            }
#pragma unroll
            for (int r = 0; r < 16; ++r) {
                int lrow = (r & 3) + 8 * (r >> 2) + 4 * kg;
                int p = base + mt * 32 + lrow;
                if (p < N_PAIRS)
                    atomicAdd(&accp[idxr[r] * 64 + ch], tanh_fast(acc[r]));
            }
        }
        __syncthreads();
    }
}

extern "C" void kernel_launch(void* const* d_in, const int* in_sizes, int n_in,
                              void* d_out, int out_size, void* d_ws, size_t ws_size,
                              hipStream_t stream) {
    const int* ind2 = (const int*)d_in[0];
    const float* prop = (const float*)d_in[1];
    const float* basis = (const float*)d_in[2];
    const float* pp0_w1 = (const float*)d_in[3];
    const float* pp0_b1 = (const float*)d_in[4];
    const float* pp_w1 = (const float*)d_in[5];
    const float* pp_b1 = (const float*)d_in[6];
    const float* pp_w2 = (const float*)d_in[7];
    const float* pp_b2 = (const float*)d_in[8];
    const float* pi_w1 = (const float*)d_in[9];
    const float* pi_b1 = (const float*)d_in[10];
    const float* pi_w2 = (const float*)d_in[11];
    const float* pi_b2 = (const float*)d_in[12];
    const float* ii_w1 = (const float*)d_in[13];
    const float* ii_w2 = (const float*)d_in[14];
    const float* res0_w = (const float*)d_in[15];
    const float* out_w1 = (const float*)d_in[16];
    const float* out_b1 = (const float*)d_in[17];
    const float* out_w2 = (const float*)d_in[18];
    const float* out_b2 = (const float*)d_in[19];
    const float* out_wo = (const float*)d_in[20];
    float* out = (float*)d_out;

    // workspace layout
    float* B0 = (float*)d_ws;                            // 25000*64 f32
    float* B1 = B0 + N_ATOMS * 64;                       // 25000*64 f32
    _Float16* Hhi = (_Float16*)(B1 + N_ATOMS * 64);      // 25000*64 f16
    _Float16* Hlo = Hhi + N_ATOMS * 64;                  // 25000*64 f16
    u16* img1 = (u16*)(Hlo + N_ATOMS * 64);              // 4*16384 u16
    u16* img2 = img1 + 4 * 16384;                        // 4*32768 u16
    u16* imgab = img2 + 4 * 32768;                       // 4*16384 u16
    float* b2p = (float*)(imgab + 4 * 16384);            // 4*256 f32
    float* pbuf[2] = {B0, B1};

    prep_kernel<<<512, 256, 0, stream>>>(pi_w1, pi_w2, ii_w1, ii_w2, img1, img2, imgab);
    prep_b2<<<4, 256, 0, stream>>>(pi_b2, b2p);

    for (int d = 0; d < DEPTH; ++d) {
        float* acc = pbuf[d & 1];
        if (d == 0) {
            atom_mlp<16, true><<<N_ATOMS / 4, 256, 0, stream>>>(
                prop, pp0_w1, pp0_b1, pp_w2, pp_b2, res0_w, Hhi, Hlo, acc);
        } else {
            const float* pin = pbuf[(d - 1) & 1];
            atom_mlp<64, false><<<N_ATOMS / 4, 256, 0, stream>>>(
                pin, pp_w1 + (d - 1) * 4096, pp_b1 + (d - 1) * 64,
                pp_w2 + d * 4096, pp_b2 + d * 64, nullptr, Hhi, Hlo, acc);
        }
        pair_kernel<<<256, 512, 0, stream>>>(
            Hhi, Hlo, ind2, basis,
            img1 + d * 16384, img2 + d * 32768, imgab + d * 16384,
            pi_b1 + d * 64, b2p + d * 256, acc);
        out_kernel<<<N_ATOMS / 4, 256, 0, stream>>>(
            acc, out_w1 + d * 4096, out_b1 + d * 64,
            out_w2 + d * 4096, out_b2 + d * 64, out_wo + d * 64,
            out, d == 0 ? 1 : 0);
    }
}

// Round 2
// 1183.017 us; speedup vs baseline: 1.1770x; 1.1770x over previous
//
#include <hip/hip_runtime.h>
#include <hip/hip_bf16.h>

#define N_ATOMS 25000
#define N_PAIRS 500000
#define DEPTH 4

typedef _Float16 f16x8 __attribute__((ext_vector_type(8)));
typedef float f32x16 __attribute__((ext_vector_type(16)));
typedef unsigned short u16;

__device__ __forceinline__ float tanh_fast(float x) {
    // tanh(x) = 1 - 2/(exp(2x)+1); saturates correctly at +/-inf
    float e = __expf(2.0f * x);
    return 1.0f - 2.0f * __builtin_amdgcn_rcpf(e + 1.0f);
}

__device__ __forceinline__ void split_h(float x, u16& hi, u16& lo) {
    _Float16 h = (_Float16)x;                 // RNE
    _Float16 l = (_Float16)(x - (float)h);    // residual, RNE
    hi = *(u16*)&h;
    lo = *(u16*)&l;
}

// LDS bank-swizzle on 16B-unit index: XOR the (ks/lh | chks/chlh) bits (u>>5)
// into the bank bits (u&7). Involution, bijective within each 128B block,
// keeps per-lane b128 units intact. Apply identically on write and read.
// Verified: SQ_LDS_BANK_CONFLICT 2.02e7 -> 0.
__device__ __forceinline__ int swz8(int u) { return u ^ ((u >> 5) & 7); }

// ---------------- prep: split weights to hi/lo fp16, fragment-major images
// img1 per depth: [hl][ntw][ks(8)][l(64)][j(8)]        = 16384 u16
// img2 per depth: [hl][ntw][t(4)][ks(4)][l][j]         = 32768 u16  (cols permuted: n=4*ch+t)
// imgab per depth: [stage][hl][ntw][ks(4)][l][j]       = 16384 u16
__global__ __launch_bounds__(256)
void prep_kernel(const float* __restrict__ piW1, const float* __restrict__ piW2,
                 const float* __restrict__ iiW1, const float* __restrict__ iiW2,
                 u16* __restrict__ img1, u16* __restrict__ img2, u16* __restrict__ imgab) {
    int gid = blockIdx.x * 256 + threadIdx.x;     // 512 blocks * 256 = 131072 = 4*32768
    int d = gid >> 15, e = gid & 32767;
    u16 hi, lo;
    if (e < 8192) {                 // W1 [k=128][n=64]
        int k = e >> 6, n = e & 63;
        split_h(piW1[d * 8192 + e], hi, lo);
        int ntw = n >> 5, colb = n & 31;
        int ks = k >> 4, lh = (k >> 3) & 1, j = k & 7;
        int off = ((ntw * 8 + ks) * 64 + lh * 32 + colb) * 8 + j;
        img1[d * 16384 + 0 * 8192 + off] = hi;
        img1[d * 16384 + 1 * 8192 + off] = lo;
    } else if (e < 24576) {         // W2 [k=64][n=256], permuted n = 4*ch + t
        int s = e - 8192;
        int k = s >> 8, n = s & 255;
        split_h(piW2[d * 16384 + s], hi, lo);
        int ch = n >> 2, t = n & 3;
        int ntw = ch >> 5, colb = ch & 31;
        int ks = k >> 4, lh = (k >> 3) & 1, j = k & 7;
        int off = (((ntw * 4 + t) * 4 + ks) * 64 + lh * 32 + colb) * 8 + j;
        img2[d * 32768 + 0 * 16384 + off] = hi;
        img2[d * 32768 + 1 * 16384 + off] = lo;
    } else {                        // Wa (stage0) / Wb (stage1), [k=64][n=64]
        int stage = (e < 28672) ? 0 : 1;
        int s = e - (stage ? 28672 : 24576);
        int k = s >> 6, n = s & 63;
        float x = stage ? iiW2[d * 4096 + s] : iiW1[d * 4096 + s];
        split_h(x, hi, lo);
        int ntw = n >> 5, colb = n & 31;
        int ks = k >> 4, lh = (k >> 3) & 1, j = k & 7;
        int off = ((ntw * 4 + ks) * 64 + lh * 32 + colb) * 8 + j;
        imgab[d * 16384 + (stage * 2 + 0) * 4096 + off] = hi;
        imgab[d * 16384 + (stage * 2 + 1) * 4096 + off] = lo;
    }
}

__global__ __launch_bounds__(256)
void prep_b2(const float* __restrict__ piB2, float* __restrict__ b2p) {
    int d = blockIdx.x, n = threadIdx.x;
    int ch = n >> 2, t = n & 3;
    int np = (ch >> 5) * 128 + t * 32 + (ch & 31);
    b2p[d * 256 + np] = piB2[d * 256 + n];
}

// ---------------- atom-level MLP (fp32 VALU), h stored split fp16 (hi=RNE, lo=RNE(h-hi))
template <int K, bool IS_D0>
__global__ __launch_bounds__(256)
void atom_mlp(const float* __restrict__ p_in,
              const float* __restrict__ W1, const float* __restrict__ b1,
              const float* __restrict__ W2, const float* __restrict__ b2,
              const float* __restrict__ res0_w,
              _Float16* __restrict__ h_hi, _Float16* __restrict__ h_lo,
              float* __restrict__ acc_out) {
    __shared__ float sP[4][64];
    __shared__ float sH[4][64];
    int tid = threadIdx.x;
    int al = tid >> 6, c = tid & 63;
    int a = blockIdx.x * 4 + al;
    if (c < K) sP[al][c] = p_in[a * K + c];
    __syncthreads();
    float s = b1[c];
#pragma unroll
    for (int k = 0; k < K; ++k) s += sP[al][k] * W1[k * 64 + c];
    float t1 = tanh_fast(s);
    float r;
    if (IS_D0) {
        r = 0.f;
#pragma unroll
        for (int k = 0; k < 16; ++k) r += sP[al][k] * res0_w[k * 64 + c];
    } else {
        r = sP[al][c];
    }
    acc_out[a * 64 + c] = r;
    sH[al][c] = t1;
    __syncthreads();
    float s2 = b2[c];
#pragma unroll
    for (int k = 0; k < 64; ++k) s2 += sH[al][k] * W2[k * 64 + c];
    float hv = tanh_fast(s2);
    _Float16 hb = (_Float16)hv;          // RNE hi
    h_hi[a * 64 + c] = hb;
    h_lo[a * 64 + c] = (_Float16)(hv - (float)hb);
}

// ---------------- output head (fp32)
__global__ __launch_bounds__(256)
void out_kernel(const float* __restrict__ p,
                const float* __restrict__ W1, const float* __restrict__ b1,
                const float* __restrict__ W2, const float* __restrict__ b2,
                const float* __restrict__ wo,
                float* __restrict__ out, int store) {
    __shared__ float sP[4][64];
    __shared__ float sH[4][64];
    int tid = threadIdx.x;
    int al = tid >> 6, c = tid & 63;
    int a = blockIdx.x * 4 + al;
    sP[al][c] = p[a * 64 + c];
    __syncthreads();
    float s = b1[c];
#pragma unroll
    for (int k = 0; k < 64; ++k) s += sP[al][k] * W1[k * 64 + c];
    sH[al][c] = tanh_fast(s);
    __syncthreads();
    float s2 = b2[c];
#pragma unroll
    for (int k = 0; k < 64; ++k) s2 += sH[al][k] * W2[k * 64 + c];
    float v = tanh_fast(s2) * wo[c];
#pragma unroll
    for (int off = 32; off > 0; off >>= 1) v += __shfl_down(v, off, 64);
    if (c == 0) {
        if (store) out[a] = v;
        else out[a] += v;
    }
}

// ---------------- fused pair pipeline: fp16 MFMA 32x32x16, split weights + split h_i
#define MFMA __builtin_amdgcn_mfma_f32_32x32x16_f16

__global__ __launch_bounds__(512, 2)
void pair_kernel(const _Float16* __restrict__ hhi,
                 const _Float16* __restrict__ hlo,
                 const int* __restrict__ ind2,
                 const float* __restrict__ basis,
                 const u16* __restrict__ img1,   // this depth
                 const u16* __restrict__ img2,
                 const u16* __restrict__ imgab,
                 const float* __restrict__ piB1,
                 const float* __restrict__ b2p,
                 float* __restrict__ accp) {
    __shared__ __attribute__((aligned(16))) _Float16 sW2[32768];   // 64 KB
    __shared__ __attribute__((aligned(16))) _Float16 sW1lo[8192];  // 16 KB  W1-lo frags (linear, conflict-free)
    __shared__ __attribute__((aligned(16))) _Float16 sA[16384];    // 32 KB  pij-hi frags / inter frags (swizzled)
    __shared__ __attribute__((aligned(16))) _Float16 sAlo[8192];   // 16 KB  pij-lo (i-half) frags (swizzled)
    __shared__ __attribute__((aligned(16))) _Float16 sPing[8192];  // 16 KB  (swizzled)
    __shared__ float sBas[128 * 4];                                //  2 KB
    __shared__ int sIdx[128];                                      // 0.5 KB
    // total 146.5 KB -> 1 block/CU, 2 waves/SIMD

    const int tid = threadIdx.x;
    for (int i = tid; i < 4096; i += 512) ((uint4*)sW2)[i] = ((const uint4*)img2)[i];
    for (int i = tid; i < 1024; i += 512) ((uint4*)sW1lo)[i] = ((const uint4*)(img1 + 8192))[i];

    const int l = tid & 63;
    const int w = tid >> 6;
    const int mt = w >> 1, ntw = w & 1;
    const int col = l & 31, kg = l >> 5;
    const int ch = ntw * 32 + col;
    const int chks = ch >> 4, chlh = (ch >> 3) & 1, chj = ch & 7;   // fragment write coords

    // persistent register weights: W1-hi (8 frags), ii_w1/ii_w2 hi+lo (16 frags)
    // NOTE: keep persistent regs at 96 VGPRs — adding W1-lo here spilled (round 1:
    // FETCH 48->217 MB scratch traffic). W1-lo stays in LDS.
    f16x8 w1h[8], fa[2][4], fb[2][4];
#pragma unroll
    for (int ks = 0; ks < 8; ++ks)
        w1h[ks] = *(const f16x8*)(img1 + ntw * 4096 + ks * 512 + l * 8);
#pragma unroll
    for (int hl = 0; hl < 2; ++hl)
#pragma unroll
        for (int ks = 0; ks < 4; ++ks) {
            fa[hl][ks] = *(const f16x8*)(imgab + (0 * 2 + hl) * 4096 + ntw * 2048 + ks * 512 + l * 8);
            fb[hl][ks] = *(const f16x8*)(imgab + (1 * 2 + hl) * 4096 + ntw * 2048 + ks * 512 + l * 8);
        }
    const float b1v = piB1[ch];
    float b2v[4];
#pragma unroll
    for (int t = 0; t < 4; ++t) b2v[t] = b2p[ntw * 128 + t * 32 + col];

    const int nTiles = (N_PAIRS + 127) >> 7;

    auto gather = [&](int tile) {
        int base = tile << 7;
#pragma unroll
        for (int it = 0; it < 6; ++it) {
            int id = it * 512 + tid;
            if (id < 2048) {            // hi: both halves, K=128
                int m = id >> 4, half = (id >> 3) & 1, seg = id & 7;
                int p = base + m;
                uint4 v = make_uint4(0u, 0u, 0u, 0u);
                if (p < N_PAIRS) {
                    int row = ind2[2 * p + half];
                    v = *(const uint4*)(hhi + row * 64 + seg * 8);
                }
                int mtd = m >> 5, lrow = m & 31;
                int ks = half * 4 + (seg >> 1), lh = seg & 1;
                int u = (mtd * 8 + ks) * 64 + lh * 32 + lrow;
                *(uint4*)(sA + swz8(u) * 8) = v;
            } else {                    // lo: i-half only, K=64
                int e = id - 2048;
                int m = e >> 3, seg = e & 7;
                int p = base + m;
                uint4 v = make_uint4(0u, 0u, 0u, 0u);
                if (p < N_PAIRS) {
                    int row = ind2[2 * p];
                    v = *(const uint4*)(hlo + row * 64 + seg * 8);
                }
                int mtd = m >> 5, lrow = m & 31;
                int ks = seg >> 1, lh = seg & 1;
                int u = (mtd * 4 + ks) * 64 + lh * 32 + lrow;
                *(uint4*)(sAlo + swz8(u) * 8) = v;
            }
        }
    };
    gather(blockIdx.x);
    __syncthreads();

    for (int tile = blockIdx.x; tile < nTiles; tile += gridDim.x) {
        const int base = tile << 7;

        // ---- G1 phase: stage basis/idx; [128x128]@[128x64]+b1, tanh -> sPing
        if (tid < 128) {
            int p = base + tid;
            float4 bv = (p < N_PAIRS) ? ((const float4*)basis)[p] : make_float4(0.f, 0.f, 0.f, 0.f);
            *(float4*)&sBas[tid * 4] = bv;
            sIdx[tid] = (p < N_PAIRS) ? ind2[2 * p] : 0;
        }
        {
            f32x16 acc = {};
            const _Float16* blo = sW1lo + ntw * 4096 + l * 8;
#pragma unroll
            for (int ks = 0; ks < 8; ++ks) {
                f16x8 a = *(const f16x8*)(sA + swz8(mt * 512 + ks * 64 + l) * 8);
                acc = MFMA(a, w1h[ks], acc, 0, 0, 0);
                acc = MFMA(a, *(const f16x8*)(blo + ks * 512), acc, 0, 0, 0);
            }
#pragma unroll
            for (int ks = 0; ks < 4; ++ks) {   // h_i lo correction (i-half = k 0..63)
                f16x8 a = *(const f16x8*)(sAlo + swz8(mt * 256 + ks * 64 + l) * 8);
                acc = MFMA(a, w1h[ks], acc, 0, 0, 0);
            }
#pragma unroll
            for (int r = 0; r < 16; ++r) {
                int lrow = (r & 3) + 8 * (r >> 2) + 4 * kg;
                int u = (mt * 4 + chks) * 64 + chlh * 32 + lrow;
                sPing[swz8(u) * 8 + chj] = (_Float16)tanh_fast(acc[r] + b1v);
            }
        }
        __syncthreads();

        // ---- G2 phase: [128x64]@[64x256]+b2, tanh, in-lane basis contraction -> sA (inter frags)
        {
            f32x16 acc[4] = {{}, {}, {}, {}};
#pragma unroll
            for (int ks = 0; ks < 4; ++ks) {
                f16x8 a = *(const f16x8*)(sPing + swz8(mt * 256 + ks * 64 + l) * 8);
#pragma unroll
                for (int t = 0; t < 4; ++t) {
                    acc[t] = MFMA(a, *(const f16x8*)(sW2 + ((ntw * 4 + t) * 4 + ks) * 512 + l * 8), acc[t], 0, 0, 0);
                    acc[t] = MFMA(a, *(const f16x8*)(sW2 + 16384 + ((ntw * 4 + t) * 4 + ks) * 512 + l * 8), acc[t], 0, 0, 0);
                }
            }
#pragma unroll
            for (int r = 0; r < 16; ++r) {
                int lrow = (r & 3) + 8 * (r >> 2) + 4 * kg;
                int row = mt * 32 + lrow;
                float4 bas = *(const float4*)&sBas[row * 4];
                float s = tanh_fast(acc[0][r] + b2v[0]) * bas.x
                        + tanh_fast(acc[1][r] + b2v[1]) * bas.y
                        + tanh_fast(acc[2][r] + b2v[2]) * bas.z
                        + tanh_fast(acc[3][r] + b2v[3]) * bas.w;
                int u = (mt * 4 + chks) * 64 + chlh * 32 + lrow;
                sA[swz8(u) * 8 + chj] = (_Float16)s;
            }
        }
        __syncthreads();

        // ---- G3 phase: inter @ ii_w1, tanh -> sPing
        {
            f32x16 acc = {};
#pragma unroll
            for (int ks = 0; ks < 4; ++ks) {
                f16x8 a = *(const f16x8*)(sA + swz8(mt * 256 + ks * 64 + l) * 8);
                acc = MFMA(a, fa[0][ks], acc, 0, 0, 0);
                acc = MFMA(a, fa[1][ks], acc, 0, 0, 0);
            }
#pragma unroll
            for (int r = 0; r < 16; ++r) {
                int lrow = (r & 3) + 8 * (r >> 2) + 4 * kg;
                int u = (mt * 4 + chks) * 64 + chlh * 32 + lrow;
                sPing[swz8(u) * 8 + chj] = (_Float16)tanh_fast(acc[r]);
            }
        }
        __syncthreads();

        // ---- G4 phase: @ ii_w2, tanh, atomic scatter; overlap next-tile gather
        {
            f16x8 afr[4];
#pragma unroll
            for (int ks = 0; ks < 4; ++ks)
                afr[ks] = *(const f16x8*)(sPing + swz8(mt * 256 + ks * 64 + l) * 8);
            int idxr[16];
#pragma unroll
            for (int r = 0; r < 16; ++r)
                idxr[r] = sIdx[mt * 32 + (r & 3) + 8 * (r >> 2) + 4 * kg];

            gather(tile + gridDim.x);   // writes sA/sAlo only (dead until next G1)

            f32x16 acc = {};
#pragma unroll
            for (int ks = 0; ks < 4; ++ks) {
                acc = MFMA(afr[ks], fb[0][ks], acc, 0, 0, 0);
                acc = MFMA(afr[ks], fb[1][ks], acc, 0, 0, 0);
            }
#pragma unroll
            for (int r = 0; r < 16; ++r) {
                int lrow = (r & 3) + 8 * (r >> 2) + 4 * kg;
                int p = base + mt * 32 + lrow;
                if (p < N_PAIRS)
                    atomicAdd(&accp[idxr[r] * 64 + ch], tanh_fast(acc[r]));
            }
        }
        __syncthreads();
    }
}

extern "C" void kernel_launch(void* const* d_in, const int* in_sizes, int n_in,
                              void* d_out, int out_size, void* d_ws, size_t ws_size,
                              hipStream_t stream) {
    const int* ind2 = (const int*)d_in[0];
    const float* prop = (const float*)d_in[1];
    const float* basis = (const float*)d_in[2];
    const float* pp0_w1 = (const float*)d_in[3];
    const float* pp0_b1 = (const float*)d_in[4];
    const float* pp_w1 = (const float*)d_in[5];
    const float* pp_b1 = (const float*)d_in[6];
    const float* pp_w2 = (const float*)d_in[7];
    const float* pp_b2 = (const float*)d_in[8];
    const float* pi_w1 = (const float*)d_in[9];
    const float* pi_b1 = (const float*)d_in[10];
    const float* pi_w2 = (const float*)d_in[11];
    const float* pi_b2 = (const float*)d_in[12];
    const float* ii_w1 = (const float*)d_in[13];
    const float* ii_w2 = (const float*)d_in[14];
    const float* res0_w = (const float*)d_in[15];
    const float* out_w1 = (const float*)d_in[16];
    const float* out_b1 = (const float*)d_in[17];
    const float* out_w2 = (const float*)d_in[18];
    const float* out_b2 = (const float*)d_in[19];
    const float* out_wo = (const float*)d_in[20];
    float* out = (float*)d_out;

    // workspace layout
    float* B0 = (float*)d_ws;                            // 25000*64 f32
    float* B1 = B0 + N_ATOMS * 64;                       // 25000*64 f32
    _Float16* Hhi = (_Float16*)(B1 + N_ATOMS * 64);      // 25000*64 f16
    _Float16* Hlo = Hhi + N_ATOMS * 64;                  // 25000*64 f16
    u16* img1 = (u16*)(Hlo + N_ATOMS * 64);              // 4*16384 u16
    u16* img2 = img1 + 4 * 16384;                        // 4*32768 u16
    u16* imgab = img2 + 4 * 32768;                       // 4*16384 u16
    float* b2p = (float*)(imgab + 4 * 16384);            // 4*256 f32
    float* pbuf[2] = {B0, B1};

    prep_kernel<<<512, 256, 0, stream>>>(pi_w1, pi_w2, ii_w1, ii_w2, img1, img2, imgab);
    prep_b2<<<4, 256, 0, stream>>>(pi_b2, b2p);

    for (int d = 0; d < DEPTH; ++d) {
        float* acc = pbuf[d & 1];
        if (d == 0) {
            atom_mlp<16, true><<<N_ATOMS / 4, 256, 0, stream>>>(
                prop, pp0_w1, pp0_b1, pp_w2, pp_b2, res0_w, Hhi, Hlo, acc);
        } else {
            const float* pin = pbuf[(d - 1) & 1];
            atom_mlp<64, false><<<N_ATOMS / 4, 256, 0, stream>>>(
                pin, pp_w1 + (d - 1) * 4096, pp_b1 + (d - 1) * 64,
                pp_w2 + d * 4096, pp_b2 + d * 64, nullptr, Hhi, Hlo, acc);
        }
        pair_kernel<<<256, 512, 0, stream>>>(
            Hhi, Hlo, ind2, basis,
            img1 + d * 16384, img2 + d * 32768, imgab + d * 16384,
            pi_b1 + d * 64, b2p + d * 256, acc);
        out_kernel<<<N_ATOMS / 4, 256, 0, stream>>>(
            acc, out_w1 + d * 4096, out_b1 + d * 64,
            out_w2 + d * 4096, out_b2 + d * 64, out_wo + d * 64,
            out, d == 0 ? 1 : 0);
    }
}

// Round 3
// 1048.330 us; speedup vs baseline: 1.3282x; 1.1285x over previous
//
#include <hip/hip_runtime.h>
#include <hip/hip_bf16.h>

#define N_ATOMS 25000
#define N_PAIRS 500000
#define DEPTH 4

typedef _Float16 f16x8 __attribute__((ext_vector_type(8)));
typedef float f32x16 __attribute__((ext_vector_type(16)));
typedef unsigned short u16;

__device__ __forceinline__ float tanh_fast(float x) {
    // tanh(x) = 1 - 2/(exp(2x)+1); saturates correctly at +/-inf
    float e = __expf(2.0f * x);
    return 1.0f - 2.0f * __builtin_amdgcn_rcpf(e + 1.0f);
}

__device__ __forceinline__ void split_h(float x, u16& hi, u16& lo) {
    _Float16 h = (_Float16)x;                 // RNE
    _Float16 l = (_Float16)(x - (float)h);    // residual, RNE
    hi = *(u16*)&h;
    lo = *(u16*)&l;
}

// LDS bank-swizzle on 16B-unit index: XOR the (ks/lh | chks/chlh) bits (u>>5)
// into the bank bits (u&7). Involution, bijective within each 128B block,
// keeps per-lane b128 units intact. Apply identically on write and read.
// Verified: SQ_LDS_BANK_CONFLICT 2.02e7 -> 0.
// In pair_kernel the swizzled addresses are expressed via 8 precomputed
// per-thread bases (rb[4], wb[4]) so the allocator doesn't hoist ~40 distinct
// address values and spill (round 2: +30MB scratch traffic).
__device__ __forceinline__ int swz8(int u) { return u ^ ((u >> 5) & 7); }

// ---------------- prep: split weights to hi/lo fp16, fragment-major images
// img1 per depth: [hl][ntw][ks(8)][l(64)][j(8)]        = 16384 u16
// img2 per depth: [hl][ntw][t(4)][ks(4)][l][j]         = 32768 u16  (cols permuted: n=4*ch+t)
// imgab per depth: [stage][hl][ntw][ks(4)][l][j]       = 16384 u16
__global__ __launch_bounds__(256)
void prep_kernel(const float* __restrict__ piW1, const float* __restrict__ piW2,
                 const float* __restrict__ iiW1, const float* __restrict__ iiW2,
                 u16* __restrict__ img1, u16* __restrict__ img2, u16* __restrict__ imgab) {
    int gid = blockIdx.x * 256 + threadIdx.x;     // 512 blocks * 256 = 131072 = 4*32768
    int d = gid >> 15, e = gid & 32767;
    u16 hi, lo;
    if (e < 8192) {                 // W1 [k=128][n=64]
        int k = e >> 6, n = e & 63;
        split_h(piW1[d * 8192 + e], hi, lo);
        int ntw = n >> 5, colb = n & 31;
        int ks = k >> 4, lh = (k >> 3) & 1, j = k & 7;
        int off = ((ntw * 8 + ks) * 64 + lh * 32 + colb) * 8 + j;
        img1[d * 16384 + 0 * 8192 + off] = hi;
        img1[d * 16384 + 1 * 8192 + off] = lo;
    } else if (e < 24576) {         // W2 [k=64][n=256], permuted n = 4*ch + t
        int s = e - 8192;
        int k = s >> 8, n = s & 255;
        split_h(piW2[d * 16384 + s], hi, lo);
        int ch = n >> 2, t = n & 3;
        int ntw = ch >> 5, colb = ch & 31;
        int ks = k >> 4, lh = (k >> 3) & 1, j = k & 7;
        int off = (((ntw * 4 + t) * 4 + ks) * 64 + lh * 32 + colb) * 8 + j;
        img2[d * 32768 + 0 * 16384 + off] = hi;
        img2[d * 32768 + 1 * 16384 + off] = lo;
    } else {                        // Wa (stage0) / Wb (stage1), [k=64][n=64]
        int stage = (e < 28672) ? 0 : 1;
        int s = e - (stage ? 28672 : 24576);
        int k = s >> 6, n = s & 63;
        float x = stage ? iiW2[d * 4096 + s] : iiW1[d * 4096 + s];
        split_h(x, hi, lo);
        int ntw = n >> 5, colb = n & 31;
        int ks = k >> 4, lh = (k >> 3) & 1, j = k & 7;
        int off = ((ntw * 4 + ks) * 64 + lh * 32 + colb) * 8 + j;
        imgab[d * 16384 + (stage * 2 + 0) * 4096 + off] = hi;
        imgab[d * 16384 + (stage * 2 + 1) * 4096 + off] = lo;
    }
}

__global__ __launch_bounds__(256)
void prep_b2(const float* __restrict__ piB2, float* __restrict__ b2p) {
    int d = blockIdx.x, n = threadIdx.x;
    int ch = n >> 2, t = n & 3;
    int np = (ch >> 5) * 128 + t * 32 + (ch & 31);
    b2p[d * 256 + np] = piB2[d * 256 + n];
}

// ---------------- atom-level MLP (fp32 VALU), h stored split fp16 (hi=RNE, lo=RNE(h-hi))
template <int K, bool IS_D0>
__global__ __launch_bounds__(256)
void atom_mlp(const float* __restrict__ p_in,
              const float* __restrict__ W1, const float* __restrict__ b1,
              const float* __restrict__ W2, const float* __restrict__ b2,
              const float* __restrict__ res0_w,
              _Float16* __restrict__ h_hi, _Float16* __restrict__ h_lo,
              float* __restrict__ acc_out) {
    __shared__ float sP[4][64];
    __shared__ float sH[4][64];
    int tid = threadIdx.x;
    int al = tid >> 6, c = tid & 63;
    int a = blockIdx.x * 4 + al;
    if (c < K) sP[al][c] = p_in[a * K + c];
    __syncthreads();
    float s = b1[c];
#pragma unroll
    for (int k = 0; k < K; ++k) s += sP[al][k] * W1[k * 64 + c];
    float t1 = tanh_fast(s);
    float r;
    if (IS_D0) {
        r = 0.f;
#pragma unroll
        for (int k = 0; k < 16; ++k) r += sP[al][k] * res0_w[k * 64 + c];
    } else {
        r = sP[al][c];
    }
    acc_out[a * 64 + c] = r;
    sH[al][c] = t1;
    __syncthreads();
    float s2 = b2[c];
#pragma unroll
    for (int k = 0; k < 64; ++k) s2 += sH[al][k] * W2[k * 64 + c];
    float hv = tanh_fast(s2);
    _Float16 hb = (_Float16)hv;          // RNE hi
    h_hi[a * 64 + c] = hb;
    h_lo[a * 64 + c] = (_Float16)(hv - (float)hb);
}

// ---------------- output head (fp32)
__global__ __launch_bounds__(256)
void out_kernel(const float* __restrict__ p,
                const float* __restrict__ W1, const float* __restrict__ b1,
                const float* __restrict__ W2, const float* __restrict__ b2,
                const float* __restrict__ wo,
                float* __restrict__ out, int store) {
    __shared__ float sP[4][64];
    __shared__ float sH[4][64];
    int tid = threadIdx.x;
    int al = tid >> 6, c = tid & 63;
    int a = blockIdx.x * 4 + al;
    sP[al][c] = p[a * 64 + c];
    __syncthreads();
    float s = b1[c];
#pragma unroll
    for (int k = 0; k < 64; ++k) s += sP[al][k] * W1[k * 64 + c];
    sH[al][c] = tanh_fast(s);
    __syncthreads();
    float s2 = b2[c];
#pragma unroll
    for (int k = 0; k < 64; ++k) s2 += sH[al][k] * W2[k * 64 + c];
    float v = tanh_fast(s2) * wo[c];
#pragma unroll
    for (int off = 32; off > 0; off >>= 1) v += __shfl_down(v, off, 64);
    if (c == 0) {
        if (store) out[a] = v;
        else out[a] += v;
    }
}

// ---------------- fused pair pipeline: fp16 MFMA 32x32x16, split weights + split h_i
#define MFMA __builtin_amdgcn_mfma_f32_32x32x16_f16

__global__ __launch_bounds__(512, 2)
void pair_kernel(const _Float16* __restrict__ hhi,
                 const _Float16* __restrict__ hlo,
                 const int* __restrict__ ind2,
                 const float* __restrict__ basis,
                 const u16* __restrict__ img1,   // this depth
                 const u16* __restrict__ img2,
                 const u16* __restrict__ imgab,
                 const float* __restrict__ piB1,
                 const float* __restrict__ b2p,
                 float* __restrict__ accp) {
    __shared__ __attribute__((aligned(16))) _Float16 sW2[32768];   // 64 KB
    __shared__ __attribute__((aligned(16))) _Float16 sW1lo[8192];  // 16 KB  W1-lo frags (linear, conflict-free)
    __shared__ __attribute__((aligned(16))) _Float16 sA[16384];    // 32 KB  pij-hi frags / inter frags (swizzled)
    __shared__ __attribute__((aligned(16))) _Float16 sAlo[8192];   // 16 KB  pij-lo (i-half) frags (swizzled)
    __shared__ __attribute__((aligned(16))) _Float16 sPing[8192];  // 16 KB  (swizzled)
    __shared__ float sBas[128 * 4];                                //  2 KB
    __shared__ int sIdx[128];                                      // 0.5 KB
    // total 146.5 KB -> 1 block/CU, 2 waves/SIMD

    const int tid = threadIdx.x;
    for (int i = tid; i < 4096; i += 512) ((uint4*)sW2)[i] = ((const uint4*)img2)[i];
    for (int i = tid; i < 1024; i += 512) ((uint4*)sW1lo)[i] = ((const uint4*)(img1 + 8192))[i];

    const int l = tid & 63;
    const int w = tid >> 6;
    const int mt = w >> 1, ntw = w & 1;
    const int col = l & 31, kg = l >> 5;
    const int ch = ntw * 32 + col;
    const int chks = ch >> 4, chlh = (ch >> 3) & 1, chj = ch & 7;   // fragment write coords

    // Precomputed swizzle bases (byte offsets). Proven equal to swz8() forms:
    //   read  addr = region + mt*stride + ks*1024 + rb[ks&3]
    //   write addr = region + wb[r&3] + (r>>2)*128
    int rb[4], wb[4];
    {
        const int wxor = 2 * chks + chlh;
#pragma unroll
        for (int c = 0; c < 4; ++c) {
            rb[c] = (l ^ (kg + 2 * c)) << 4;
            wb[c] = (mt * 4 + chks) * 1024 + chlh * 512 + ((((c) + 4 * kg) ^ wxor) << 4) + chj * 2;
        }
    }
    const int mtsA = mt << 13;   // mt*8192: G1 sA region stride
    const int mts  = mt << 12;   // mt*4096: 256-unit-stride regions

    // persistent register weights: W1-hi (8 frags), ii_w1/ii_w2 hi+lo (16 frags)
    // NOTE: keep persistent regs at ~96+8 VGPRs — adding W1-lo here spilled
    // (round 1: FETCH 48->217 MB scratch traffic). W1-lo stays in LDS.
    f16x8 w1h[8], fa[2][4], fb[2][4];
#pragma unroll
    for (int ks = 0; ks < 8; ++ks)
        w1h[ks] = *(const f16x8*)(img1 + ntw * 4096 + ks * 512 + l * 8);
#pragma unroll
    for (int hl = 0; hl < 2; ++hl)
#pragma unroll
        for (int ks = 0; ks < 4; ++ks) {
            fa[hl][ks] = *(const f16x8*)(imgab + (0 * 2 + hl) * 4096 + ntw * 2048 + ks * 512 + l * 8);
            fb[hl][ks] = *(const f16x8*)(imgab + (1 * 2 + hl) * 4096 + ntw * 2048 + ks * 512 + l * 8);
        }
    const float b1v = piB1[ch];
    float b2v[4];
#pragma unroll
    for (int t = 0; t < 4; ++t) b2v[t] = b2p[ntw * 128 + t * 32 + col];

    const int nTiles = (N_PAIRS + 127) >> 7;

    auto gather = [&](int tile) {
        int base = tile << 7;
#pragma unroll
        for (int it = 0; it < 6; ++it) {
            int id = it * 512 + tid;
            if (id < 2048) {            // hi: both halves, K=128
                int m = id >> 4, half = (id >> 3) & 1, seg = id & 7;
                int p = base + m;
                uint4 v = make_uint4(0u, 0u, 0u, 0u);
                if (p < N_PAIRS) {
                    int row = ind2[2 * p + half];
                    v = *(const uint4*)(hhi + row * 64 + seg * 8);
                }
                int mtd = m >> 5, lrow = m & 31;
                int ks = half * 4 + (seg >> 1), lh = seg & 1;
                int u = (mtd * 8 + ks) * 64 + lh * 32 + lrow;
                *(uint4*)(sA + swz8(u) * 8) = v;
            } else {                    // lo: i-half only, K=64
                int e = id - 2048;
                int m = e >> 3, seg = e & 7;
                int p = base + m;
                uint4 v = make_uint4(0u, 0u, 0u, 0u);
                if (p < N_PAIRS) {
                    int row = ind2[2 * p];
                    v = *(const uint4*)(hlo + row * 64 + seg * 8);
                }
                int mtd = m >> 5, lrow = m & 31;
                int ks = seg >> 1, lh = seg & 1;
                int u = (mtd * 4 + ks) * 64 + lh * 32 + lrow;
                *(uint4*)(sAlo + swz8(u) * 8) = v;
            }
        }
    };
    gather(blockIdx.x);
    __syncthreads();

    for (int tile = blockIdx.x; tile < nTiles; tile += gridDim.x) {
        const int base = tile << 7;

        // ---- G1 phase: stage basis/idx; [128x128]@[128x64]+b1, tanh -> sPing
        if (tid < 128) {
            int p = base + tid;
            float4 bv = (p < N_PAIRS) ? ((const float4*)basis)[p] : make_float4(0.f, 0.f, 0.f, 0.f);
            *(float4*)&sBas[tid * 4] = bv;
            sIdx[tid] = (p < N_PAIRS) ? ind2[2 * p] : 0;
        }
        {
            f32x16 acc = {};
            const char* blo = (const char*)(sW1lo + ntw * 4096 + l * 8);
#pragma unroll
            for (int ks = 0; ks < 8; ++ks) {
                f16x8 a = *(const f16x8*)((const char*)sA + mtsA + ks * 1024 + rb[ks & 3]);
                acc = MFMA(a, w1h[ks], acc, 0, 0, 0);
                acc = MFMA(a, *(const f16x8*)(blo + ks * 1024), acc, 0, 0, 0);
            }
#pragma unroll
            for (int ks = 0; ks < 4; ++ks) {   // h_i lo correction (i-half = k 0..63)
                f16x8 a = *(const f16x8*)((const char*)sAlo + mts + ks * 1024 + rb[ks]);
                acc = MFMA(a, w1h[ks], acc, 0, 0, 0);
            }
#pragma unroll
            for (int r = 0; r < 16; ++r)
                *(u16*)((char*)sPing + wb[r & 3] + ((r >> 2) << 7)) =
                    __builtin_bit_cast(u16, (_Float16)tanh_fast(acc[r] + b1v));
        }
        __syncthreads();

        // ---- G2 phase: [128x64]@[64x256]+b2, tanh, in-lane basis contraction -> sA (inter frags)
        {
            f32x16 acc[4] = {{}, {}, {}, {}};
#pragma unroll
            for (int ks = 0; ks < 4; ++ks) {
                f16x8 a = *(const f16x8*)((const char*)sPing + mts + ks * 1024 + rb[ks]);
#pragma unroll
                for (int t = 0; t < 4; ++t) {
                    acc[t] = MFMA(a, *(const f16x8*)(sW2 + ((ntw * 4 + t) * 4 + ks) * 512 + l * 8), acc[t], 0, 0, 0);
                    acc[t] = MFMA(a, *(const f16x8*)(sW2 + 16384 + ((ntw * 4 + t) * 4 + ks) * 512 + l * 8), acc[t], 0, 0, 0);
                }
            }
#pragma unroll
            for (int r = 0; r < 16; ++r) {
                int lrow = (r & 3) + 8 * (r >> 2) + 4 * kg;
                int row = mt * 32 + lrow;
                float4 bas = *(const float4*)&sBas[row * 4];
                float s = tanh_fast(acc[0][r] + b2v[0]) * bas.x
                        + tanh_fast(acc[1][r] + b2v[1]) * bas.y
                        + tanh_fast(acc[2][r] + b2v[2]) * bas.z
                        + tanh_fast(acc[3][r] + b2v[3]) * bas.w;
                *(u16*)((char*)sA + wb[r & 3] + ((r >> 2) << 7)) =
                    __builtin_bit_cast(u16, (_Float16)s);
            }
        }
        __syncthreads();

        // ---- G3 phase: inter @ ii_w1, tanh -> sPing
        {
            f32x16 acc = {};
#pragma unroll
            for (int ks = 0; ks < 4; ++ks) {
                f16x8 a = *(const f16x8*)((const char*)sA + mts + ks * 1024 + rb[ks]);
                acc = MFMA(a, fa[0][ks], acc, 0, 0, 0);
                acc = MFMA(a, fa[1][ks], acc, 0, 0, 0);
            }
#pragma unroll
            for (int r = 0; r < 16; ++r)
                *(u16*)((char*)sPing + wb[r & 3] + ((r >> 2) << 7)) =
                    __builtin_bit_cast(u16, (_Float16)tanh_fast(acc[r]));
        }
        __syncthreads();

        // ---- G4 phase: @ ii_w2, tanh, atomic scatter; overlap next-tile gather
        {
            f16x8 afr[4];
#pragma unroll
            for (int ks = 0; ks < 4; ++ks)
                afr[ks] = *(const f16x8*)((const char*)sPing + mts + ks * 1024 + rb[ks]);

            gather(tile + gridDim.x);   // writes sA/sAlo only (dead until next G1)

            f32x16 acc = {};
#pragma unroll
            for (int ks = 0; ks < 4; ++ks) {
                acc = MFMA(afr[ks], fb[0][ks], acc, 0, 0, 0);
                acc = MFMA(afr[ks], fb[1][ks], acc, 0, 0, 0);
            }
#pragma unroll
            for (int r = 0; r < 16; ++r) {
                int lrow = (r & 3) + 8 * (r >> 2) + 4 * kg;
                int p = base + mt * 32 + lrow;
                if (p < N_PAIRS)
                    atomicAdd(&accp[sIdx[mt * 32 + lrow] * 64 + ch], tanh_fast(acc[r]));
            }
        }
        __syncthreads();
    }
}

extern "C" void kernel_launch(void* const* d_in, const int* in_sizes, int n_in,
                              void* d_out, int out_size, void* d_ws, size_t ws_size,
                              hipStream_t stream) {
    const int* ind2 = (const int*)d_in[0];
    const float* prop = (const float*)d_in[1];
    const float* basis = (const float*)d_in[2];
    const float* pp0_w1 = (const float*)d_in[3];
    const float* pp0_b1 = (const float*)d_in[4];
    const float* pp_w1 = (const float*)d_in[5];
    const float* pp_b1 = (const float*)d_in[6];
    const float* pp_w2 = (const float*)d_in[7];
    const float* pp_b2 = (const float*)d_in[8];
    const float* pi_w1 = (const float*)d_in[9];
    const float* pi_b1 = (const float*)d_in[10];
    const float* pi_w2 = (const float*)d_in[11];
    const float* pi_b2 = (const float*)d_in[12];
    const float* ii_w1 = (const float*)d_in[13];
    const float* ii_w2 = (const float*)d_in[14];
    const float* res0_w = (const float*)d_in[15];
    const float* out_w1 = (const float*)d_in[16];
    const float* out_b1 = (const float*)d_in[17];
    const float* out_w2 = (const float*)d_in[18];
    const float* out_b2 = (const float*)d_in[19];
    const float* out_wo = (const float*)d_in[20];
    float* out = (float*)d_out;

    // workspace layout
    float* B0 = (float*)d_ws;                            // 25000*64 f32
    float* B1 = B0 + N_ATOMS * 64;                       // 25000*64 f32
    _Float16* Hhi = (_Float16*)(B1 + N_ATOMS * 64);      // 25000*64 f16
    _Float16* Hlo = Hhi + N_ATOMS * 64;                  // 25000*64 f16
    u16* img1 = (u16*)(Hlo + N_ATOMS * 64);              // 4*16384 u16
    u16* img2 = img1 + 4 * 16384;                        // 4*32768 u16
    u16* imgab = img2 + 4 * 32768;                       // 4*16384 u16
    float* b2p = (float*)(imgab + 4 * 16384);            // 4*256 f32
    float* pbuf[2] = {B0, B1};

    prep_kernel<<<512, 256, 0, stream>>>(pi_w1, pi_w2, ii_w1, ii_w2, img1, img2, imgab);
    prep_b2<<<4, 256, 0, stream>>>(pi_b2, b2p);

    for (int d = 0; d < DEPTH; ++d) {
        float* acc = pbuf[d & 1];
        if (d == 0) {
            atom_mlp<16, true><<<N_ATOMS / 4, 256, 0, stream>>>(
                prop, pp0_w1, pp0_b1, pp_w2, pp_b2, res0_w, Hhi, Hlo, acc);
        } else {
            const float* pin = pbuf[(d - 1) & 1];
            atom_mlp<64, false><<<N_ATOMS / 4, 256, 0, stream>>>(
                pin, pp_w1 + (d - 1) * 4096, pp_b1 + (d - 1) * 64,
                pp_w2 + d * 4096, pp_b2 + d * 64, nullptr, Hhi, Hlo, acc);
        }
        pair_kernel<<<256, 512, 0, stream>>>(
            Hhi, Hlo, ind2, basis,
            img1 + d * 16384, img2 + d * 32768, imgab + d * 16384,
            pi_b1 + d * 64, b2p + d * 256, acc);
        out_kernel<<<N_ATOMS / 4, 256, 0, stream>>>(
            acc, out_w1 + d * 4096, out_b1 + d * 64,
            out_w2 + d * 4096, out_b2 + d * 64, out_wo + d * 64,
            out, d == 0 ? 1 : 0);
    }
}

// Round 4
// 1043.384 us; speedup vs baseline: 1.3345x; 1.0047x over previous
//
#include <hip/hip_runtime.h>
#include <hip/hip_bf16.h>

#define N_ATOMS 25000
#define N_PAIRS 500000
#define DEPTH 4

typedef _Float16 f16x8 __attribute__((ext_vector_type(8)));
typedef float f32x16 __attribute__((ext_vector_type(16)));
typedef unsigned short u16;

__device__ __forceinline__ float tanh_fast(float x) {
    // tanh(x) = 1 - 2/(exp(2x)+1); saturates correctly at +/-inf
    float e = __expf(2.0f * x);
    return 1.0f - 2.0f * __builtin_amdgcn_rcpf(e + 1.0f);
}

__device__ __forceinline__ void split_h(float x, u16& hi, u16& lo) {
    _Float16 h = (_Float16)x;                 // RNE
    _Float16 l = (_Float16)(x - (float)h);    // residual, RNE
    hi = *(u16*)&h;
    lo = *(u16*)&l;
}

// LDS-only barrier: drains lgkmcnt (LDS) but NOT vmcnt, so fire-and-forget
// global atomics stay in flight across phase boundaries. All inter-phase
// communication in pair_kernel is through LDS, so lgkmcnt(0) suffices.
__device__ __forceinline__ void bar_lgkm() {
    asm volatile("s_waitcnt lgkmcnt(0)" ::: "memory");
    __builtin_amdgcn_s_barrier();
}

// LDS bank-swizzle on 16B-unit index: XOR the (ks/lh | chks/chlh) bits (u>>5)
// into the bank bits (u&7). Involution, bijective within each 128B block,
// keeps per-lane b128 units intact. Apply identically on write and read.
// Verified: SQ_LDS_BANK_CONFLICT 2.02e7 -> 0.
// In pair_kernel the swizzled addresses are expressed via 8 precomputed
// per-thread bases (rb[4], wb[4]) so the allocator doesn't hoist ~40 distinct
// address values and spill (round 2: +30MB scratch traffic).
__device__ __forceinline__ int swz8(int u) { return u ^ ((u >> 5) & 7); }

// ---------------- prep: split weights to hi/lo fp16, fragment-major images
// img1 per depth: [hl][ntw][ks(8)][l(64)][j(8)]        = 16384 u16
// img2 per depth: [hl][ntw][t(4)][ks(4)][l][j]         = 32768 u16  (cols permuted: n=4*ch+t)
// imgab per depth: [stage][hl][ntw][ks(4)][l][j]       = 16384 u16
__global__ __launch_bounds__(256)
void prep_kernel(const float* __restrict__ piW1, const float* __restrict__ piW2,
                 const float* __restrict__ iiW1, const float* __restrict__ iiW2,
                 u16* __restrict__ img1, u16* __restrict__ img2, u16* __restrict__ imgab) {
    int gid = blockIdx.x * 256 + threadIdx.x;     // 512 blocks * 256 = 131072 = 4*32768
    int d = gid >> 15, e = gid & 32767;
    u16 hi, lo;
    if (e < 8192) {                 // W1 [k=128][n=64]
        int k = e >> 6, n = e & 63;
        split_h(piW1[d * 8192 + e], hi, lo);
        int ntw = n >> 5, colb = n & 31;
        int ks = k >> 4, lh = (k >> 3) & 1, j = k & 7;
        int off = ((ntw * 8 + ks) * 64 + lh * 32 + colb) * 8 + j;
        img1[d * 16384 + 0 * 8192 + off] = hi;
        img1[d * 16384 + 1 * 8192 + off] = lo;
    } else if (e < 24576) {         // W2 [k=64][n=256], permuted n = 4*ch + t
        int s = e - 8192;
        int k = s >> 8, n = s & 255;
        split_h(piW2[d * 16384 + s], hi, lo);
        int ch = n >> 2, t = n & 3;
        int ntw = ch >> 5, colb = ch & 31;
        int ks = k >> 4, lh = (k >> 3) & 1, j = k & 7;
        int off = (((ntw * 4 + t) * 4 + ks) * 64 + lh * 32 + colb) * 8 + j;
        img2[d * 32768 + 0 * 16384 + off] = hi;
        img2[d * 32768 + 1 * 16384 + off] = lo;
    } else {                        // Wa (stage0) / Wb (stage1), [k=64][n=64]
        int stage = (e < 28672) ? 0 : 1;
        int s = e - (stage ? 28672 : 24576);
        int k = s >> 6, n = s & 63;
        float x = stage ? iiW2[d * 4096 + s] : iiW1[d * 4096 + s];
        split_h(x, hi, lo);
        int ntw = n >> 5, colb = n & 31;
        int ks = k >> 4, lh = (k >> 3) & 1, j = k & 7;
        int off = ((ntw * 4 + ks) * 64 + lh * 32 + colb) * 8 + j;
        imgab[d * 16384 + (stage * 2 + 0) * 4096 + off] = hi;
        imgab[d * 16384 + (stage * 2 + 1) * 4096 + off] = lo;
    }
}

__global__ __launch_bounds__(256)
void prep_b2(const float* __restrict__ piB2, float* __restrict__ b2p) {
    int d = blockIdx.x, n = threadIdx.x;
    int ch = n >> 2, t = n & 3;
    int np = (ch >> 5) * 128 + t * 32 + (ch & 31);
    b2p[d * 256 + np] = piB2[d * 256 + n];
}

// ---------------- atom-level MLP (fp32 VALU), h stored split fp16 (hi=RNE, lo=RNE(h-hi))
template <int K, bool IS_D0>
__global__ __launch_bounds__(256)
void atom_mlp(const float* __restrict__ p_in,
              const float* __restrict__ W1, const float* __restrict__ b1,
              const float* __restrict__ W2, const float* __restrict__ b2,
              const float* __restrict__ res0_w,
              _Float16* __restrict__ h_hi, _Float16* __restrict__ h_lo,
              float* __restrict__ acc_out) {
    __shared__ float sP[4][64];
    __shared__ float sH[4][64];
    int tid = threadIdx.x;
    int al = tid >> 6, c = tid & 63;
    int a = blockIdx.x * 4 + al;
    if (c < K) sP[al][c] = p_in[a * K + c];
    __syncthreads();
    float s = b1[c];
#pragma unroll
    for (int k = 0; k < K; ++k) s += sP[al][k] * W1[k * 64 + c];
    float t1 = tanh_fast(s);
    float r;
    if (IS_D0) {
        r = 0.f;
#pragma unroll
        for (int k = 0; k < 16; ++k) r += sP[al][k] * res0_w[k * 64 + c];
    } else {
        r = sP[al][c];
    }
    acc_out[a * 64 + c] = r;
    sH[al][c] = t1;
    __syncthreads();
    float s2 = b2[c];
#pragma unroll
    for (int k = 0; k < 64; ++k) s2 += sH[al][k] * W2[k * 64 + c];
    float hv = tanh_fast(s2);
    _Float16 hb = (_Float16)hv;          // RNE hi
    h_hi[a * 64 + c] = hb;
    h_lo[a * 64 + c] = (_Float16)(hv - (float)hb);
}

// ---------------- output head (fp32), standalone (used after last depth)
__global__ __launch_bounds__(256)
void out_kernel(const float* __restrict__ p,
                const float* __restrict__ W1, const float* __restrict__ b1,
                const float* __restrict__ W2, const float* __restrict__ b2,
                const float* __restrict__ wo,
                float* __restrict__ out, int store) {
    __shared__ float sP[4][64];
    __shared__ float sH[4][64];
    int tid = threadIdx.x;
    int al = tid >> 6, c = tid & 63;
    int a = blockIdx.x * 4 + al;
    sP[al][c] = p[a * 64 + c];
    __syncthreads();
    float s = b1[c];
#pragma unroll
    for (int k = 0; k < 64; ++k) s += sP[al][k] * W1[k * 64 + c];
    sH[al][c] = tanh_fast(s);
    __syncthreads();
    float s2 = b2[c];
#pragma unroll
    for (int k = 0; k < 64; ++k) s2 += sH[al][k] * W2[k * 64 + c];
    float v = tanh_fast(s2) * wo[c];
#pragma unroll
    for (int off = 32; off > 0; off >>= 1) v += __shfl_down(v, off, 64);
    if (c == 0) {
        if (store) out[a] = v;
        else out[a] += v;
    }
}

// ---------------- fused: out head of depth d + atom MLP of depth d+1
// Both read the same p -> one staging pass, one launch instead of two.
__global__ __launch_bounds__(256)
void fused_out_atom(const float* __restrict__ p,
                    const float* __restrict__ oW1, const float* __restrict__ ob1,
                    const float* __restrict__ oW2, const float* __restrict__ ob2,
                    const float* __restrict__ wo,
                    const float* __restrict__ aW1, const float* __restrict__ ab1,
                    const float* __restrict__ aW2, const float* __restrict__ ab2,
                    float* __restrict__ out, int store,
                    _Float16* __restrict__ h_hi, _Float16* __restrict__ h_lo,
                    float* __restrict__ acc_out) {
    __shared__ float sP[4][64];
    __shared__ float sHo[4][64];
    __shared__ float sHa[4][64];
    int tid = threadIdx.x;
    int al = tid >> 6, c = tid & 63;
    int a = blockIdx.x * 4 + al;
    float pv = p[a * 64 + c];
    sP[al][c] = pv;
    acc_out[a * 64 + c] = pv;            // residual base for next depth
    __syncthreads();
    float so = ob1[c], sa = ab1[c];
#pragma unroll
    for (int k = 0; k < 64; ++k) {
        float x = sP[al][k];
        so += x * oW1[k * 64 + c];
        sa += x * aW1[k * 64 + c];
    }
    sHo[al][c] = tanh_fast(so);
    sHa[al][c] = tanh_fast(sa);
    __syncthreads();
    float s2o = ob2[c], s2a = ab2[c];
#pragma unroll
    for (int k = 0; k < 64; ++k) {
        s2o += sHo[al][k] * oW2[k * 64 + c];
        s2a += sHa[al][k] * aW2[k * 64 + c];
    }
    float v = tanh_fast(s2o) * wo[c];
#pragma unroll
    for (int off = 32; off > 0; off >>= 1) v += __shfl_down(v, off, 64);
    if (c == 0) {
        if (store) out[a] = v;
        else out[a] += v;
    }
    float hv = tanh_fast(s2a);
    _Float16 hb = (_Float16)hv;          // RNE hi
    h_hi[a * 64 + c] = hb;
    h_lo[a * 64 + c] = (_Float16)(hv - (float)hb);
}

// ---------------- fused pair pipeline: fp16 MFMA 32x32x16, split weights + split h_i
#define MFMA __builtin_amdgcn_mfma_f32_32x32x16_f16

__global__ __launch_bounds__(512, 2)
void pair_kernel(const _Float16* __restrict__ hhi,
                 const _Float16* __restrict__ hlo,
                 const int* __restrict__ ind2,
                 const float* __restrict__ basis,
                 const u16* __restrict__ img1,   // this depth
                 const u16* __restrict__ img2,
                 const u16* __restrict__ imgab,
                 const float* __restrict__ piB1,
                 const float* __restrict__ b2p,
                 float* __restrict__ accp) {
    __shared__ __attribute__((aligned(16))) _Float16 sW2[32768];   // 64 KB
    __shared__ __attribute__((aligned(16))) _Float16 sW1lo[8192];  // 16 KB  W1-lo frags (linear, conflict-free)
    __shared__ __attribute__((aligned(16))) _Float16 sA[16384];    // 32 KB  pij-hi frags / inter frags (swizzled)
    __shared__ __attribute__((aligned(16))) _Float16 sAlo[8192];   // 16 KB  pij-lo (i-half) frags (swizzled)
    __shared__ __attribute__((aligned(16))) _Float16 sPing[8192];  // 16 KB  (swizzled)
    __shared__ float sBas[2][128 * 4];                             //  4 KB  (double-buffered)
    __shared__ int sIdx[2][128];                                   //  1 KB  (double-buffered)
    // total 149 KB -> 1 block/CU, 2 waves/SIMD

    const int tid = threadIdx.x;
    for (int i = tid; i < 4096; i += 512) ((uint4*)sW2)[i] = ((const uint4*)img2)[i];
    for (int i = tid; i < 1024; i += 512) ((uint4*)sW1lo)[i] = ((const uint4*)(img1 + 8192))[i];

    const int l = tid & 63;
    const int w = tid >> 6;
    const int mt = w >> 1, ntw = w & 1;
    const int col = l & 31, kg = l >> 5;
    const int ch = ntw * 32 + col;
    const int chks = ch >> 4, chlh = (ch >> 3) & 1, chj = ch & 7;   // fragment write coords

    // Precomputed swizzle bases (byte offsets). Proven equal to swz8() forms:
    //   read  addr = region + mt*stride + ks*1024 + rb[ks&3]
    //   write addr = region + wb[r&3] + (r>>2)*128
    int rb[4], wb[4];
    {
        const int wxor = 2 * chks + chlh;
#pragma unroll
        for (int c = 0; c < 4; ++c) {
            rb[c] = (l ^ (kg + 2 * c)) << 4;
            wb[c] = (mt * 4 + chks) * 1024 + chlh * 512 + ((((c) + 4 * kg) ^ wxor) << 4) + chj * 2;
        }
    }
    const int mtsA = mt << 13;   // mt*8192: G1 sA region stride
    const int mts  = mt << 12;   // mt*4096: 256-unit-stride regions

    // persistent register weights: W1-hi (8 frags), ii_w1/ii_w2 hi+lo (16 frags)
    // NOTE: keep persistent regs at ~96+8 VGPRs — adding W1-lo here spilled
    // (round 1: FETCH 48->217 MB scratch traffic). W1-lo stays in LDS.
    f16x8 w1h[8], fa[2][4], fb[2][4];
#pragma unroll
    for (int ks = 0; ks < 8; ++ks)
        w1h[ks] = *(const f16x8*)(img1 + ntw * 4096 + ks * 512 + l * 8);
#pragma unroll
    for (int hl = 0; hl < 2; ++hl)
#pragma unroll
        for (int ks = 0; ks < 4; ++ks) {
            fa[hl][ks] = *(const f16x8*)(imgab + (0 * 2 + hl) * 4096 + ntw * 2048 + ks * 512 + l * 8);
            fb[hl][ks] = *(const f16x8*)(imgab + (1 * 2 + hl) * 4096 + ntw * 2048 + ks * 512 + l * 8);
        }
    const float b1v = piB1[ch];
    float b2v[4];
#pragma unroll
    for (int t = 0; t < 4; ++t) b2v[t] = b2p[ntw * 128 + t * 32 + col];

    const int nTiles = (N_PAIRS + 127) >> 7;

    // gather: stage pair fragments AND per-tile meta (basis/idx) for `tile`
    // into LDS buffer `pb`. Only vmem loads in the steady-state loop besides
    // the G4 atomics.
    auto gather = [&](int tile, int pb) {
        int base = tile << 7;
        if (tid < 128) {
            int p = base + tid;
            float4 bv = (p < N_PAIRS) ? ((const float4*)basis)[p] : make_float4(0.f, 0.f, 0.f, 0.f);
            *(float4*)&sBas[pb][tid * 4] = bv;
            sIdx[pb][tid] = (p < N_PAIRS) ? ind2[2 * p] : 0;
        }
#pragma unroll
        for (int it = 0; it < 6; ++it) {
            int id = it * 512 + tid;
            if (id < 2048) {            // hi: both halves, K=128
                int m = id >> 4, half = (id >> 3) & 1, seg = id & 7;
                int p = base + m;
                uint4 v = make_uint4(0u, 0u, 0u, 0u);
                if (p < N_PAIRS) {
                    int row = ind2[2 * p + half];
                    v = *(const uint4*)(hhi + row * 64 + seg * 8);
                }
                int mtd = m >> 5, lrow = m & 31;
                int ks = half * 4 + (seg >> 1), lh = seg & 1;
                int u = (mtd * 8 + ks) * 64 + lh * 32 + lrow;
                *(uint4*)(sA + swz8(u) * 8) = v;
            } else {                    // lo: i-half only, K=64
                int e = id - 2048;
                int m = e >> 3, seg = e & 7;
                int p = base + m;
                uint4 v = make_uint4(0u, 0u, 0u, 0u);
                if (p < N_PAIRS) {
                    int row = ind2[2 * p];
                    v = *(const uint4*)(hlo + row * 64 + seg * 8);
                }
                int mtd = m >> 5, lrow = m & 31;
                int ks = seg >> 1, lh = seg & 1;
                int u = (mtd * 4 + ks) * 64 + lh * 32 + lrow;
                *(uint4*)(sAlo + swz8(u) * 8) = v;
            }
        }
    };
    gather(blockIdx.x, 0);
    __syncthreads();

    int pb = 0;
    for (int tile = blockIdx.x; tile < nTiles; tile += gridDim.x) {
        const int base = tile << 7;

        // ---- G1 phase: [128x128]@[128x64]+b1, tanh -> sPing
        {
            f32x16 acc = {};
            const char* blo = (const char*)(sW1lo + ntw * 4096 + l * 8);
#pragma unroll
            for (int ks = 0; ks < 8; ++ks) {
                f16x8 a = *(const f16x8*)((const char*)sA + mtsA + ks * 1024 + rb[ks & 3]);
                acc = MFMA(a, w1h[ks], acc, 0, 0, 0);
                acc = MFMA(a, *(const f16x8*)(blo + ks * 1024), acc, 0, 0, 0);
            }
#pragma unroll
            for (int ks = 0; ks < 4; ++ks) {   // h_i lo correction (i-half = k 0..63)
                f16x8 a = *(const f16x8*)((const char*)sAlo + mts + ks * 1024 + rb[ks]);
                acc = MFMA(a, w1h[ks], acc, 0, 0, 0);
            }
#pragma unroll
            for (int r = 0; r < 16; ++r)
                *(u16*)((char*)sPing + wb[r & 3] + ((r >> 2) << 7)) =
                    __builtin_bit_cast(u16, (_Float16)tanh_fast(acc[r] + b1v));
        }
        bar_lgkm();

        // ---- G2 phase: [128x64]@[64x256]+b2, tanh, in-lane basis contraction -> sA (inter frags)
        {
            f32x16 acc[4] = {{}, {}, {}, {}};
#pragma unroll
            for (int ks = 0; ks < 4; ++ks) {
                f16x8 a = *(const f16x8*)((const char*)sPing + mts + ks * 1024 + rb[ks]);
#pragma unroll
                for (int t = 0; t < 4; ++t) {
                    acc[t] = MFMA(a, *(const f16x8*)(sW2 + ((ntw * 4 + t) * 4 + ks) * 512 + l * 8), acc[t], 0, 0, 0);
                    acc[t] = MFMA(a, *(const f16x8*)(sW2 + 16384 + ((ntw * 4 + t) * 4 + ks) * 512 + l * 8), acc[t], 0, 0, 0);
                }
            }
#pragma unroll
            for (int r = 0; r < 16; ++r) {
                int lrow = (r & 3) + 8 * (r >> 2) + 4 * kg;
                int row = mt * 32 + lrow;
                float4 bas = *(const float4*)&sBas[pb][row * 4];
                float s = tanh_fast(acc[0][r] + b2v[0]) * bas.x
                        + tanh_fast(acc[1][r] + b2v[1]) * bas.y
                        + tanh_fast(acc[2][r] + b2v[2]) * bas.z
                        + tanh_fast(acc[3][r] + b2v[3]) * bas.w;
                *(u16*)((char*)sA + wb[r & 3] + ((r >> 2) << 7)) =
                    __builtin_bit_cast(u16, (_Float16)s);
            }
        }
        bar_lgkm();

        // ---- G3 phase: inter @ ii_w1, tanh -> sPing
        {
            f32x16 acc = {};
#pragma unroll
            for (int ks = 0; ks < 4; ++ks) {
                f16x8 a = *(const f16x8*)((const char*)sA + mts + ks * 1024 + rb[ks]);
                acc = MFMA(a, fa[0][ks], acc, 0, 0, 0);
                acc = MFMA(a, fa[1][ks], acc, 0, 0, 0);
            }
#pragma unroll
            for (int r = 0; r < 16; ++r)
                *(u16*)((char*)sPing + wb[r & 3] + ((r >> 2) << 7)) =
                    __builtin_bit_cast(u16, (_Float16)tanh_fast(acc[r]));
        }
        bar_lgkm();

        // ---- G4 phase: @ ii_w2, tanh, atomic scatter; overlap next-tile gather.
        // Atomics are issued LAST (youngest vmem) and never drained in-loop:
        // the next wait that implies their completion is the NEXT G4's gather
        // ds_write vmcnt wait — a full tile of compute later.
        {
            f16x8 afr[4];
#pragma unroll
            for (int ks = 0; ks < 4; ++ks)
                afr[ks] = *(const f16x8*)((const char*)sPing + mts + ks * 1024 + rb[ks]);

            gather(tile + gridDim.x, pb ^ 1);   // writes sA/sAlo + meta[pb^1] (dead until next G1/G2)

            f32x16 acc = {};
#pragma unroll
            for (int ks = 0; ks < 4; ++ks) {
                acc = MFMA(afr[ks], fb[0][ks], acc, 0, 0, 0);
                acc = MFMA(afr[ks], fb[1][ks], acc, 0, 0, 0);
            }
#pragma unroll
            for (int r = 0; r < 16; ++r) {
                int lrow = (r & 3) + 8 * (r >> 2) + 4 * kg;
                int p = base + mt * 32 + lrow;
                if (p < N_PAIRS)
                    atomicAdd(&accp[sIdx[pb][mt * 32 + lrow] * 64 + ch], tanh_fast(acc[r]));
            }
        }
        bar_lgkm();
        pb ^= 1;
    }
}

extern "C" void kernel_launch(void* const* d_in, const int* in_sizes, int n_in,
                              void* d_out, int out_size, void* d_ws, size_t ws_size,
                              hipStream_t stream) {
    const int* ind2 = (const int*)d_in[0];
    const float* prop = (const float*)d_in[1];
    const float* basis = (const float*)d_in[2];
    const float* pp0_w1 = (const float*)d_in[3];
    const float* pp0_b1 = (const float*)d_in[4];
    const float* pp_w1 = (const float*)d_in[5];
    const float* pp_b1 = (const float*)d_in[6];
    const float* pp_w2 = (const float*)d_in[7];
    const float* pp_b2 = (const float*)d_in[8];
    const float* pi_w1 = (const float*)d_in[9];
    const float* pi_b1 = (const float*)d_in[10];
    const float* pi_w2 = (const float*)d_in[11];
    const float* pi_b2 = (const float*)d_in[12];
    const float* ii_w1 = (const float*)d_in[13];
    const float* ii_w2 = (const float*)d_in[14];
    const float* res0_w = (const float*)d_in[15];
    const float* out_w1 = (const float*)d_in[16];
    const float* out_b1 = (const float*)d_in[17];
    const float* out_w2 = (const float*)d_in[18];
    const float* out_b2 = (const float*)d_in[19];
    const float* out_wo = (const float*)d_in[20];
    float* out = (float*)d_out;

    // workspace layout
    float* B0 = (float*)d_ws;                            // 25000*64 f32
    float* B1 = B0 + N_ATOMS * 64;                       // 25000*64 f32
    _Float16* Hhi = (_Float16*)(B1 + N_ATOMS * 64);      // 25000*64 f16
    _Float16* Hlo = Hhi + N_ATOMS * 64;                  // 25000*64 f16
    u16* img1 = (u16*)(Hlo + N_ATOMS * 64);              // 4*16384 u16
    u16* img2 = img1 + 4 * 16384;                        // 4*32768 u16
    u16* imgab = img2 + 4 * 32768;                       // 4*16384 u16
    float* b2p = (float*)(imgab + 4 * 16384);            // 4*256 f32
    float* pbuf[2] = {B0, B1};

    prep_kernel<<<512, 256, 0, stream>>>(pi_w1, pi_w2, ii_w1, ii_w2, img1, img2, imgab);
    prep_b2<<<4, 256, 0, stream>>>(pi_b2, b2p);

    for (int d = 0; d < DEPTH; ++d) {
        float* acc = pbuf[d & 1];
        if (d == 0) {
            atom_mlp<16, true><<<N_ATOMS / 4, 256, 0, stream>>>(
                prop, pp0_w1, pp0_b1, pp_w2, pp_b2, res0_w, Hhi, Hlo, acc);
        } else {
            // fused: out head of depth d-1 (reads p_d = pbuf[(d-1)&1]) + atom MLP of depth d
            const float* pin = pbuf[(d - 1) & 1];
            fused_out_atom<<<N_ATOMS / 4, 256, 0, stream>>>(
                pin,
                out_w1 + (d - 1) * 4096, out_b1 + (d - 1) * 64,
                out_w2 + (d - 1) * 4096, out_b2 + (d - 1) * 64, out_wo + (d - 1) * 64,
                pp_w1 + (d - 1) * 4096, pp_b1 + (d - 1) * 64,
                pp_w2 + d * 4096, pp_b2 + d * 64,
                out, (d - 1) == 0 ? 1 : 0,
                Hhi, Hlo, acc);
        }
        pair_kernel<<<256, 512, 0, stream>>>(
            Hhi, Hlo, ind2, basis,
            img1 + d * 16384, img2 + d * 32768, imgab + d * 16384,
            pi_b1 + d * 64, b2p + d * 256, acc);
    }
    out_kernel<<<N_ATOMS / 4, 256, 0, stream>>>(
        pbuf[(DEPTH - 1) & 1], out_w1 + (DEPTH - 1) * 4096, out_b1 + (DEPTH - 1) * 64,
        out_w2 + (DEPTH - 1) * 4096, out_b2 + (DEPTH - 1) * 64, out_wo + (DEPTH - 1) * 64,
        out, 0);
}